// Round 21
// baseline (503.293 us; speedup 1.0000x reference)
//
#include <hip/hip_runtime.h>
#include <math.h>

#define F_IN 1433
#define F_HID 16
#define F_OUT 7
#define CAP 128     // padded CSR row capacity; max in-degree ~60 for Poisson(32)
#define NKT 45      // ceil(1433/32) k-tiles
#define KTFULL 44   // full 32-wide k-tiles

#define AS1 __attribute__((address_space(1)))
#define AS3 __attribute__((address_space(3)))

typedef __attribute__((ext_vector_type(8))) short bf16x8;
typedef __attribute__((ext_vector_type(4))) float f32x4;

__device__ __forceinline__ void gload_lds16(const float* gp, float* lp) {
  __builtin_amdgcn_global_load_lds((const AS1 void*)gp, (AS3 void*)lp, 16, 0, 0);
}

__device__ __forceinline__ unsigned short f2bf(float f) {
  unsigned u = __float_as_uint(f);
  u += 0x7fffu + ((u >> 16) & 1u);  // RNE
  return (unsigned short)(u >> 16);
}

__device__ __forceinline__ unsigned pk2(float a, float b) {
  return (unsigned)f2bf(a) | ((unsigned)f2bf(b) << 16);
}

__device__ __forceinline__ void upk_add(unsigned u, float& lo, float& hi) {
  lo += __uint_as_float(u << 16);
  hi += __uint_as_float(u & 0xffff0000u);
}

// ---- prep: zero cnt (blocks [0,nzb)) + pack W1 into B-fragment order -------
__global__ __launch_bounds__(256) void k_prep(const float* __restrict__ W1,
                                              int* __restrict__ cnt,
                                              uint4* __restrict__ W1f, int N,
                                              int nzb) {
  const int b = blockIdx.x, t = threadIdx.x;
  if (b < nzb) {
    const int i = b * 256 + t;
    if (i < N) cnt[i] = 0;
    return;
  }
  if (t >= 64) return;
  const int tile = b - nzb;
  const int kg = t >> 4, n = t & 15;
  unsigned u[4];
#pragma unroll
  for (int p = 0; p < 4; ++p) {
    const int k0 = tile * 32 + kg * 8 + 2 * p;
    const float a = (k0 < F_IN) ? W1[k0 * F_HID + n] : 0.0f;
    const float bb = (k0 + 1 < F_IN) ? W1[(k0 + 1) * F_HID + n] : 0.0f;
    u[p] = pk2(a, bb);
  }
  W1f[tile * 64 + t] = make_uint4(u[0], u[1], u[2], u[3]);
}

// ---- solo CSR scatter: csr[d*CAP + r] = src, r via returning atomic --------
__global__ __launch_bounds__(256) void k_scatter(const int* __restrict__ src,
                                                 const int* __restrict__ dst,
                                                 int* __restrict__ cnt,
                                                 int* __restrict__ csr, int E) {
  const int e4 = blockIdx.x * 256 + threadIdx.x;
  const int base = e4 * 4;
  if (base + 3 < E) {
    const int4 s = *(const int4*)(src + base);
    const int4 d = *(const int4*)(dst + base);
    int r;
    r = atomicAdd(&cnt[d.x], 1); csr[((size_t)d.x << 7) + r] = s.x;
    r = atomicAdd(&cnt[d.y], 1); csr[((size_t)d.y << 7) + r] = s.y;
    r = atomicAdd(&cnt[d.z], 1); csr[((size_t)d.z << 7) + r] = s.z;
    r = atomicAdd(&cnt[d.w], 1); csr[((size_t)d.w << 7) + r] = s.w;
  } else {
    for (int k = base; k < E; ++k) {
      const int d = dst[k];
      const int r = atomicAdd(&cnt[d], 1);
      csr[((size_t)d << 7) + r] = src[k];
    }
  }
}

// ---- solo STAGED MFMA GEMM: 64 rows/block, global_load_lds + XOR swizzle ---
__global__ __launch_bounds__(256) void k_gemmS(const float* __restrict__ x,
                                               const uint4* __restrict__ W1f,
                                               float* __restrict__ h1f, int N) {
  __shared__ float xs[2 * 2048];  // 2 bufs x 64 rows x 32 cols f32 = 16KB
  const int t = threadIdx.x;
  const int row0g = blockIdx.x * 64;
  if (row0g >= N) return;
  const int w = t >> 6;   // wave 0..3 (owns rows w*16..w*16+15)
  const int l = t & 63;
  const int m = l & 15;   // node row within m-tile AND feature col of C/D
  const int kg = l >> 4;  // k-group 0..3

  const int s_swz = (l & 7) ^ (l >> 3);

#define STAGE(BUF, KT)                                                       \
  do {                                                                       \
    _Pragma("unroll") for (int r_ = 0; r_ < 2; ++r_) {                       \
      const int rloc_ = w * 8 + (l >> 3) + r_ * 32;                          \
      const int grow_ = row0g + rloc_;                                       \
      float* lp_ = xs + (BUF) * 2048 + r_ * 1024 + w * 256;                  \
      if (grow_ < N)                                                         \
        gload_lds16(x + (size_t)grow_ * F_IN + (KT) * 32 + s_swz * 4, lp_);  \
    }                                                                        \
  } while (0)

  f32x4 acc = {0.f, 0.f, 0.f, 0.f};
  const int rloc = w * 16 + m;
  const int c0 = (2 * kg) ^ (m & 7);
  const int c1 = (2 * kg + 1) ^ (m & 7);

  STAGE(0, 0);
  __syncthreads();
  for (int kt = 0; kt < KTFULL; ++kt) {
    const int cur = kt & 1;
    if (kt + 1 < KTFULL) STAGE(cur ^ 1, kt + 1);
    const float* xrow = xs + cur * 2048 + rloc * 32;
    const float4 fa = *(const float4*)(xrow + c0 * 4);
    const float4 fb = *(const float4*)(xrow + c1 * 4);
    union { unsigned uu[4]; bf16x8 v; } av;
    av.uu[0] = pk2(fa.x, fa.y);
    av.uu[1] = pk2(fa.z, fa.w);
    av.uu[2] = pk2(fb.x, fb.y);
    av.uu[3] = pk2(fb.z, fb.w);
    union { uint4 q; bf16x8 v; } wv;
    wv.q = W1f[kt * 64 + l];
    acc = __builtin_amdgcn_mfma_f32_16x16x32_bf16(av.v, wv.v, acc, 0, 0, 0);
    __syncthreads();  // reads of cur done + next stage landed
  }
#undef STAGE
  {  // tail k-tile (k >= 1408): direct per-lane global loads, zero-padded
    int rowA = row0g + w * 16 + m;
    if (rowA >= N) rowA = N - 1;
    const float* __restrict__ xr = x + (size_t)rowA * F_IN;
    const int k0 = KTFULL * 32 + kg * 8;
    float e[8];
#pragma unroll
    for (int j = 0; j < 8; ++j) {
      const int k = k0 + j;
      e[j] = (k < F_IN) ? xr[k] : 0.0f;
    }
    union { unsigned uu[4]; bf16x8 v; } av;
    av.uu[0] = pk2(e[0], e[1]);
    av.uu[1] = pk2(e[2], e[3]);
    av.uu[2] = pk2(e[4], e[5]);
    av.uu[3] = pk2(e[6], e[7]);
    union { uint4 q; bf16x8 v; } wv;
    wv.q = W1f[KTFULL * 64 + l];
    acc = __builtin_amdgcn_mfma_f32_16x16x32_bf16(av.v, wv.v, acc, 0, 0, 0);
  }
  // C/D layout (m89-verified): col = l&15 (feature), row = (l>>4)*4 + r (node)
#pragma unroll
  for (int r = 0; r < 4; ++r) {
    const int orow = row0g + w * 16 + kg * 4 + r;
    if (orow < N) h1f[(size_t)orow * F_HID + m] = acc[r];
  }
}

// ---- scale h1f by dis=rsqrt(deg+1), pack to bf16 (uint4 = 8 bf16) ----------
__global__ __launch_bounds__(256) void k_scale(const float4* __restrict__ h1f,
                                               const int* __restrict__ cnt,
                                               uint4* __restrict__ h1v, int N) {
  const int idx = blockIdx.x * 256 + threadIdx.x;  // over 2N halves
  if (idx >= 2 * N) return;
  const int node = idx >> 1;
  const float sc = rsqrtf((float)(cnt[node] + 1));
  const float4 a = h1f[idx * 2];
  const float4 b = h1f[idx * 2 + 1];
  uint4 o;
  o.x = pk2(a.x * sc, a.y * sc);
  o.y = pk2(a.z * sc, a.w * sc);
  o.z = pk2(b.x * sc, b.y * sc);
  o.w = pk2(b.z * sc, b.w * sc);
  h1v[idx] = o;
}

// ---- layer1 per-node finish: reduce slots, +self, MLP, store bf16 ----------
__device__ __forceinline__ void l1_finish(float a[8], int i, int d, int lane,
                                          int p, const uint4* __restrict__ h1v,
                                          const float* __restrict__ b1,
                                          const float* __restrict__ W2,
                                          uint4* __restrict__ h2v) {
#pragma unroll
  for (int m = 2; m <= 32; m <<= 1) {
#pragma unroll
    for (int j = 0; j < 8; ++j) a[j] += __shfl_xor(a[j], m);
  }
  const uint4 v = h1v[((size_t)i << 1) + p];
  upk_add(v.x, a[0], a[1]);
  upk_add(v.y, a[2], a[3]);
  upk_add(v.z, a[4], a[5]);
  upk_add(v.w, a[6], a[7]);
  const float sd = rsqrtf((float)(d + 1));
  const float4 bl = ((const float4*)b1)[p * 2];
  const float4 bh = ((const float4*)b1)[p * 2 + 1];
  float tt[8];
  tt[0] = fmaxf(fmaf(a[0], sd, bl.x), 0.f);
  tt[1] = fmaxf(fmaf(a[1], sd, bl.y), 0.f);
  tt[2] = fmaxf(fmaf(a[2], sd, bl.z), 0.f);
  tt[3] = fmaxf(fmaf(a[3], sd, bl.w), 0.f);
  tt[4] = fmaxf(fmaf(a[4], sd, bh.x), 0.f);
  tt[5] = fmaxf(fmaf(a[5], sd, bh.y), 0.f);
  tt[6] = fmaxf(fmaf(a[6], sd, bh.z), 0.f);
  tt[7] = fmaxf(fmaf(a[7], sd, bh.w), 0.f);
  const float* __restrict__ w = W2 + p * 8 * F_OUT;
  float o[F_OUT];
#pragma unroll
  for (int j = 0; j < F_OUT; ++j) {
    o[j] = tt[0] * w[0 * F_OUT + j] + tt[1] * w[1 * F_OUT + j] +
           tt[2] * w[2 * F_OUT + j] + tt[3] * w[3 * F_OUT + j] +
           tt[4] * w[4 * F_OUT + j] + tt[5] * w[5 * F_OUT + j] +
           tt[6] * w[6 * F_OUT + j] + tt[7] * w[7 * F_OUT + j];
  }
#pragma unroll
  for (int j = 0; j < F_OUT; ++j) o[j] += __shfl_xor(o[j], 1);
  if (lane == 0) {
    uint4 r;
    r.x = pk2(o[0] * sd, o[1] * sd);
    r.y = pk2(o[2] * sd, o[3] * sd);
    r.z = pk2(o[4] * sd, o[5] * sd);
    r.w = pk2(o[6] * sd, 0.0f);
    h2v[i] = r;
  }
}

// ---- layer1 gather: one wave = TWO nodes x TWO neighbor-batches ------------
__global__ __launch_bounds__(256) void k_agg1n(
    const int* __restrict__ cnt, const int* __restrict__ csr,
    const uint4* __restrict__ h1v, const float* __restrict__ b1,
    const float* __restrict__ W2, uint4* __restrict__ h2v, int N) {
  const int lane = threadIdx.x & 63;
  const int i0 = blockIdx.x * 8 + (threadIdx.x >> 6) * 2;
  if (i0 >= N) return;
  const int i1 = i0 + 1;
  const bool has1 = (i1 < N);
  const int nb = lane >> 1;
  const int p = lane & 1;

  const int d0 = cnt[i0];
  const int d1 = has1 ? cnt[i1] : 0;
  const int* __restrict__ row0 = csr + ((size_t)i0 << 7);
  const int* __restrict__ row1 = csr + ((size_t)i1 << 7);

  float A[8], B[8];
#pragma unroll
  for (int j = 0; j < 8; ++j) { A[j] = 0.f; B[j] = 0.f; }
  const int dm = max(d0, d1);
  for (int c0 = 0; c0 < dm; c0 += 64) {
    const int cA = c0 + nb;
    const int cB = cA + 32;
    const int s0a = (cA < d0) ? row0[cA] : -1;
    const int s0b = (cB < d0) ? row0[cB] : -1;
    const int s1a = (cA < d1) ? row1[cA] : -1;
    const int s1b = (cB < d1) ? row1[cB] : -1;
    if (s0a >= 0) {
      const uint4 v = h1v[((size_t)s0a << 1) + p];
      upk_add(v.x, A[0], A[1]); upk_add(v.y, A[2], A[3]);
      upk_add(v.z, A[4], A[5]); upk_add(v.w, A[6], A[7]);
    }
    if (s0b >= 0) {
      const uint4 v = h1v[((size_t)s0b << 1) + p];
      upk_add(v.x, A[0], A[1]); upk_add(v.y, A[2], A[3]);
      upk_add(v.z, A[4], A[5]); upk_add(v.w, A[6], A[7]);
    }
    if (s1a >= 0) {
      const uint4 v = h1v[((size_t)s1a << 1) + p];
      upk_add(v.x, B[0], B[1]); upk_add(v.y, B[2], B[3]);
      upk_add(v.z, B[4], B[5]); upk_add(v.w, B[6], B[7]);
    }
    if (s1b >= 0) {
      const uint4 v = h1v[((size_t)s1b << 1) + p];
      upk_add(v.x, B[0], B[1]); upk_add(v.y, B[2], B[3]);
      upk_add(v.z, B[4], B[5]); upk_add(v.w, B[6], B[7]);
    }
  }
  l1_finish(A, i0, d0, lane, p, h1v, b1, W2, h2v);
  if (has1) l1_finish(B, i1, d1, lane, p, h1v, b1, W2, h2v);
}

// ---- layer2 per-node finish: reduce, +self, bias, log_softmax, store -------
__device__ __forceinline__ void l2_finish(float a[8], int i, int d, int lane,
                                          const uint4* __restrict__ h2v,
                                          const float* __restrict__ b2,
                                          float* __restrict__ out) {
#pragma unroll
  for (int m = 1; m <= 32; m <<= 1) {
#pragma unroll
    for (int j = 0; j < 7; ++j) a[j] += __shfl_xor(a[j], m);
  }
  const uint4 v = h2v[i];
  upk_add(v.x, a[0], a[1]);
  upk_add(v.y, a[2], a[3]);
  upk_add(v.z, a[4], a[5]);
  float dummy = 0.f;
  upk_add(v.w, a[6], dummy);
  if (lane == 0) {
    const float sd = rsqrtf((float)(d + 1));
    float vv[7];
#pragma unroll
    for (int j = 0; j < 7; ++j) vv[j] = fmaf(a[j], sd, b2[j]);
    float m = fmaxf(fmaxf(fmaxf(vv[0], vv[1]), fmaxf(vv[2], vv[3])),
                    fmaxf(fmaxf(vv[4], vv[5]), vv[6]));
    float sum = 0.f;
#pragma unroll
    for (int j = 0; j < 7; ++j) sum += expf(vv[j] - m);
    const float l = m + logf(sum);
    float* __restrict__ op = out + (size_t)i * F_OUT;
#pragma unroll
    for (int j = 0; j < 7; ++j) op[j] = vv[j] - l;
  }
}

// ---- layer2 gather: one wave = TWO nodes, indices hoisted ahead of gathers -
__global__ __launch_bounds__(256) void k_agg2n(const int* __restrict__ cnt,
                                               const int* __restrict__ csr,
                                               const uint4* __restrict__ h2v,
                                               const float* __restrict__ b2,
                                               float* __restrict__ out, int N) {
  const int lane = threadIdx.x & 63;
  const int i0 = blockIdx.x * 8 + (threadIdx.x >> 6) * 2;
  if (i0 >= N) return;
  const int i1 = i0 + 1;
  const bool has1 = (i1 < N);

  const int d0 = cnt[i0];
  const int d1 = has1 ? cnt[i1] : 0;
  const int* __restrict__ row0 = csr + ((size_t)i0 << 7);
  const int* __restrict__ row1 = csr + ((size_t)i1 << 7);

  float A[8], B[8];
#pragma unroll
  for (int j = 0; j < 8; ++j) { A[j] = 0.f; B[j] = 0.f; }
  const int dm = max(d0, d1);
  for (int c0 = 0; c0 < dm; c0 += 64) {
    const int c = c0 + lane;
    const int sA = (c < d0) ? row0[c] : -1;
    const int sB = (c < d1) ? row1[c] : -1;
    if (sA >= 0) {
      const uint4 v = h2v[sA];
      upk_add(v.x, A[0], A[1]); upk_add(v.y, A[2], A[3]);
      upk_add(v.z, A[4], A[5]); upk_add(v.w, A[6], A[7]);
    }
    if (sB >= 0) {
      const uint4 v = h2v[sB];
      upk_add(v.x, B[0], B[1]); upk_add(v.y, B[2], B[3]);
      upk_add(v.z, B[4], B[5]); upk_add(v.w, B[6], B[7]);
    }
  }
  l2_finish(A, i0, d0, lane, h2v, b2, out);
  if (has1) l2_finish(B, i1, d1, lane, h2v, b2, out);
}

extern "C" void kernel_launch(void* const* d_in, const int* in_sizes, int n_in,
                              void* d_out, int out_size, void* d_ws,
                              size_t ws_size, hipStream_t stream) {
  const float* x = (const float*)d_in[0];
  const int* ei = (const int*)d_in[1];
  const float* W1 = (const float*)d_in[2];
  const float* b1 = (const float*)d_in[3];
  const float* W2 = (const float*)d_in[4];
  const float* b2 = (const float*)d_in[5];

  const int N = in_sizes[0] / F_IN;
  const int E = in_sizes[1] / 2;
  const int* src = ei;
  const int* dst = ei + E;

  // ws: h1f[16N f32] | h1b[16N bf16] | h2b[8N bf16] | cnt[N] | csr[N*CAP] | W1f
  float* h1f = (float*)d_ws;
  unsigned short* h1b = (unsigned short*)(h1f + (size_t)16 * N);
  unsigned short* h2b = h1b + (size_t)16 * N;
  int* cnt = (int*)(h2b + (size_t)8 * N);
  int* csr = cnt + N;
  uint4* W1f = (uint4*)(csr + (size_t)N * CAP);
  float* out = (float*)d_out;

  const int B = 256;
  const int nzb = (N + B - 1) / B;        // 391
  const int ne4 = (E + 3) / 4;
  const int ngb = (N + 63) / 64;          // gemm blocks (64 rows each)

  k_prep<<<nzb + NKT, B, 0, stream>>>(W1, cnt, W1f, N, nzb);
  k_scatter<<<(ne4 + B - 1) / B, B, 0, stream>>>(src, dst, cnt, csr, E);
  k_gemmS<<<ngb, B, 0, stream>>>(x, W1f, h1f, N);
  k_scale<<<(2 * N + B - 1) / B, B, 0, stream>>>((const float4*)h1f, cnt,
                                                 (uint4*)h1b, N);
  k_agg1n<<<(N + 7) / 8, B, 0, stream>>>(cnt, csr, (const uint4*)h1b, b1, W2,
                                         (uint4*)h2b, N);
  k_agg2n<<<(N + 7) / 8, B, 0, stream>>>(cnt, csr, (const uint4*)h2b, b2, out,
                                         N);
}

// Round 22
// 405.523 us; speedup vs baseline: 1.2411x; 1.2411x over previous
//
#include <hip/hip_runtime.h>
#include <math.h>

#define F_IN 1433
#define F_HID 16
#define F_OUT 7
#define CAP 128     // padded CSR row capacity; max in-degree ~60 for Poisson(32)
#define NSCAT 512   // grid-stride scatter blocks (dispatched first)
#define NKT 45      // ceil(1433/32) k-tiles
#define KTFULL 44   // full 32-wide k-tiles

#define AS1 __attribute__((address_space(1)))
#define AS3 __attribute__((address_space(3)))

typedef __attribute__((ext_vector_type(8))) short bf16x8;
typedef __attribute__((ext_vector_type(4))) float f32x4;

__device__ __forceinline__ void gload_lds16(const float* gp, float* lp) {
  __builtin_amdgcn_global_load_lds((const AS1 void*)gp, (AS3 void*)lp, 16, 0, 0);
}

__device__ __forceinline__ unsigned short f2bf(float f) {
  unsigned u = __float_as_uint(f);
  u += 0x7fffu + ((u >> 16) & 1u);  // RNE
  return (unsigned short)(u >> 16);
}

__device__ __forceinline__ unsigned pk2(float a, float b) {
  return (unsigned)f2bf(a) | ((unsigned)f2bf(b) << 16);
}

__device__ __forceinline__ void upk_add(unsigned u, float& lo, float& hi) {
  lo += __uint_as_float(u << 16);
  hi += __uint_as_float(u & 0xffff0000u);
}

// ---- prep: zero cnt (blocks [0,nzb)) + pack W1 into B-fragment order -------
__global__ __launch_bounds__(256) void k_prep(const float* __restrict__ W1,
                                              int* __restrict__ cnt,
                                              uint4* __restrict__ W1f, int N,
                                              int nzb) {
  const int b = blockIdx.x, t = threadIdx.x;
  if (b < nzb) {
    const int i = b * 256 + t;
    if (i < N) cnt[i] = 0;
    return;
  }
  if (t >= 64) return;
  const int tile = b - nzb;
  const int kg = t >> 4, n = t & 15;
  unsigned u[4];
#pragma unroll
  for (int p = 0; p < 4; ++p) {
    const int k0 = tile * 32 + kg * 8 + 2 * p;
    const float a = (k0 < F_IN) ? W1[k0 * F_HID + n] : 0.0f;
    const float bb = (k0 + 1 < F_IN) ? W1[(k0 + 1) * F_HID + n] : 0.0f;
    u[p] = pk2(a, bb);
  }
  W1f[tile * 64 + t] = make_uint4(u[0], u[1], u[2], u[3]);
}

// ==== FUSED: blocks [0,NSCAT) = grid-stride CSR scatter; rest = MFMA GEMM ===
// GEMM: 64 rows/block, LDS-staged x via global_load_lds(16B) with XOR-
// swizzled GLOBAL source + linear LDS dest; ds_read applies same XOR.
__global__ __launch_bounds__(256) void k_fused(
    const float* __restrict__ x, const uint4* __restrict__ W1f,
    const int* __restrict__ src, const int* __restrict__ dst,
    int* __restrict__ cnt, int* __restrict__ csr, float* __restrict__ h1f,
    int N, int E) {
  __shared__ float xs[2 * 2048];  // 2 bufs x 64 rows x 32 cols f32 = 16KB
  const int t = threadIdx.x;
  const int b = blockIdx.x;

  if (b < NSCAT) {
    const int ne4 = (E + 3) >> 2;
    for (int i4 = b * 256 + t; i4 < ne4; i4 += NSCAT * 256) {
      const int base = i4 * 4;
      if (base + 3 < E) {
        const int4 s = *(const int4*)(src + base);
        const int4 d = *(const int4*)(dst + base);
        int r;
        r = atomicAdd(&cnt[d.x], 1); csr[((size_t)d.x << 7) + r] = s.x;
        r = atomicAdd(&cnt[d.y], 1); csr[((size_t)d.y << 7) + r] = s.y;
        r = atomicAdd(&cnt[d.z], 1); csr[((size_t)d.z << 7) + r] = s.z;
        r = atomicAdd(&cnt[d.w], 1); csr[((size_t)d.w << 7) + r] = s.w;
      } else {
        for (int k = base; k < E; ++k) {
          const int d = dst[k];
          const int r = atomicAdd(&cnt[d], 1);
          csr[((size_t)d << 7) + r] = src[k];
        }
      }
    }
    return;
  }

  // ---- gemm role ----
  const int g = b - NSCAT;
  const int row0g = g * 64;
  if (row0g >= N) return;
  const int w = t >> 6;   // wave 0..3 (owns rows w*16..w*16+15)
  const int l = t & 63;
  const int m = l & 15;   // node row within m-tile AND feature col of C/D
  const int kg = l >> 4;  // k-group 0..3

  const int s_swz = (l & 7) ^ (l >> 3);

#define STAGE(BUF, KT)                                                       \
  do {                                                                       \
    _Pragma("unroll") for (int r_ = 0; r_ < 2; ++r_) {                       \
      const int rloc_ = w * 8 + (l >> 3) + r_ * 32;                          \
      const int grow_ = row0g + rloc_;                                       \
      float* lp_ = xs + (BUF) * 2048 + r_ * 1024 + w * 256;                  \
      if (grow_ < N)                                                         \
        gload_lds16(x + (size_t)grow_ * F_IN + (KT) * 32 + s_swz * 4, lp_);  \
    }                                                                        \
  } while (0)

  f32x4 acc = {0.f, 0.f, 0.f, 0.f};
  const int rloc = w * 16 + m;
  const int c0 = (2 * kg) ^ (m & 7);
  const int c1 = (2 * kg + 1) ^ (m & 7);

  STAGE(0, 0);
  __syncthreads();
  for (int kt = 0; kt < KTFULL; ++kt) {
    const int cur = kt & 1;
    if (kt + 1 < KTFULL) STAGE(cur ^ 1, kt + 1);
    const float* xrow = xs + cur * 2048 + rloc * 32;
    const float4 fa = *(const float4*)(xrow + c0 * 4);
    const float4 fb = *(const float4*)(xrow + c1 * 4);
    union { unsigned uu[4]; bf16x8 v; } av;
    av.uu[0] = pk2(fa.x, fa.y);
    av.uu[1] = pk2(fa.z, fa.w);
    av.uu[2] = pk2(fb.x, fb.y);
    av.uu[3] = pk2(fb.z, fb.w);
    union { uint4 q; bf16x8 v; } wv;
    wv.q = W1f[kt * 64 + l];
    acc = __builtin_amdgcn_mfma_f32_16x16x32_bf16(av.v, wv.v, acc, 0, 0, 0);
    __syncthreads();  // reads of cur done + next stage landed
  }
#undef STAGE
  {  // tail k-tile (k >= 1408): direct per-lane global loads, zero-padded
    int rowA = row0g + w * 16 + m;
    if (rowA >= N) rowA = N - 1;
    const float* __restrict__ xr = x + (size_t)rowA * F_IN;
    const int k0 = KTFULL * 32 + kg * 8;
    float e[8];
#pragma unroll
    for (int j = 0; j < 8; ++j) {
      const int k = k0 + j;
      e[j] = (k < F_IN) ? xr[k] : 0.0f;
    }
    union { unsigned uu[4]; bf16x8 v; } av;
    av.uu[0] = pk2(e[0], e[1]);
    av.uu[1] = pk2(e[2], e[3]);
    av.uu[2] = pk2(e[4], e[5]);
    av.uu[3] = pk2(e[6], e[7]);
    union { uint4 q; bf16x8 v; } wv;
    wv.q = W1f[KTFULL * 64 + l];
    acc = __builtin_amdgcn_mfma_f32_16x16x32_bf16(av.v, wv.v, acc, 0, 0, 0);
  }
  // C/D layout (m89-verified): col = l&15 (feature), row = (l>>4)*4 + r (node)
#pragma unroll
  for (int r = 0; r < 4; ++r) {
    const int orow = row0g + w * 16 + kg * 4 + r;
    if (orow < N) h1f[(size_t)orow * F_HID + m] = acc[r];
  }
}

// ---- scale h1f by dis=rsqrt(deg+1), pack to bf16 (uint4 = 8 bf16) ----------
__global__ __launch_bounds__(256) void k_scale(const float4* __restrict__ h1f,
                                               const int* __restrict__ cnt,
                                               uint4* __restrict__ h1v, int N) {
  const int idx = blockIdx.x * 256 + threadIdx.x;  // over 2N halves
  if (idx >= 2 * N) return;
  const int node = idx >> 1;
  const float sc = rsqrtf((float)(cnt[node] + 1));
  const float4 a = h1f[idx * 2];
  const float4 b = h1f[idx * 2 + 1];
  uint4 o;
  o.x = pk2(a.x * sc, a.y * sc);
  o.y = pk2(a.z * sc, a.w * sc);
  o.z = pk2(b.x * sc, b.y * sc);
  o.w = pk2(b.z * sc, b.w * sc);
  h1v[idx] = o;
}

// ---- layer1 per-node finish: reduce slots, +self, MLP, store bf16 ----------
__device__ __forceinline__ void l1_finish(float a[8], int i, int d, int lane,
                                          int p, const uint4* __restrict__ h1v,
                                          const float* __restrict__ b1,
                                          const float* __restrict__ W2,
                                          uint4* __restrict__ h2v) {
#pragma unroll
  for (int m = 2; m <= 32; m <<= 1) {
#pragma unroll
    for (int j = 0; j < 8; ++j) a[j] += __shfl_xor(a[j], m);
  }
  const uint4 v = h1v[((size_t)i << 1) + p];
  upk_add(v.x, a[0], a[1]);
  upk_add(v.y, a[2], a[3]);
  upk_add(v.z, a[4], a[5]);
  upk_add(v.w, a[6], a[7]);
  const float sd = rsqrtf((float)(d + 1));
  const float4 bl = ((const float4*)b1)[p * 2];
  const float4 bh = ((const float4*)b1)[p * 2 + 1];
  float tt[8];
  tt[0] = fmaxf(fmaf(a[0], sd, bl.x), 0.f);
  tt[1] = fmaxf(fmaf(a[1], sd, bl.y), 0.f);
  tt[2] = fmaxf(fmaf(a[2], sd, bl.z), 0.f);
  tt[3] = fmaxf(fmaf(a[3], sd, bl.w), 0.f);
  tt[4] = fmaxf(fmaf(a[4], sd, bh.x), 0.f);
  tt[5] = fmaxf(fmaf(a[5], sd, bh.y), 0.f);
  tt[6] = fmaxf(fmaf(a[6], sd, bh.z), 0.f);
  tt[7] = fmaxf(fmaf(a[7], sd, bh.w), 0.f);
  const float* __restrict__ w = W2 + p * 8 * F_OUT;
  float o[F_OUT];
#pragma unroll
  for (int j = 0; j < F_OUT; ++j) {
    o[j] = tt[0] * w[0 * F_OUT + j] + tt[1] * w[1 * F_OUT + j] +
           tt[2] * w[2 * F_OUT + j] + tt[3] * w[3 * F_OUT + j] +
           tt[4] * w[4 * F_OUT + j] + tt[5] * w[5 * F_OUT + j] +
           tt[6] * w[6 * F_OUT + j] + tt[7] * w[7 * F_OUT + j];
  }
#pragma unroll
  for (int j = 0; j < F_OUT; ++j) o[j] += __shfl_xor(o[j], 1);
  if (lane == 0) {
    uint4 r;
    r.x = pk2(o[0] * sd, o[1] * sd);
    r.y = pk2(o[2] * sd, o[3] * sd);
    r.z = pk2(o[4] * sd, o[5] * sd);
    r.w = pk2(o[6] * sd, 0.0f);
    h2v[i] = r;
  }
}

// ---- layer1 gather: one wave = TWO nodes x TWO neighbor-batches ------------
// 4 independent csr->h1 chains in flight; stride-64 loop = ~1 iteration for
// Poisson(32) degrees.
__global__ __launch_bounds__(256) void k_agg1n(
    const int* __restrict__ cnt, const int* __restrict__ csr,
    const uint4* __restrict__ h1v, const float* __restrict__ b1,
    const float* __restrict__ W2, uint4* __restrict__ h2v, int N) {
  const int lane = threadIdx.x & 63;
  const int i0 = blockIdx.x * 8 + (threadIdx.x >> 6) * 2;
  if (i0 >= N) return;
  const int i1 = i0 + 1;
  const bool has1 = (i1 < N);
  const int nb = lane >> 1;
  const int p = lane & 1;

  const int d0 = cnt[i0];
  const int d1 = has1 ? cnt[i1] : 0;
  const int* __restrict__ row0 = csr + ((size_t)i0 << 7);
  const int* __restrict__ row1 = csr + ((size_t)i1 << 7);

  float A[8], B[8];
#pragma unroll
  for (int j = 0; j < 8; ++j) { A[j] = 0.f; B[j] = 0.f; }
  const int dm = max(d0, d1);
  for (int c0 = 0; c0 < dm; c0 += 64) {
    const int cA = c0 + nb;
    const int cB = cA + 32;
    // all four index loads issue before any gather (4 independent chains)
    const int s0a = (cA < d0) ? row0[cA] : -1;
    const int s0b = (cB < d0) ? row0[cB] : -1;
    const int s1a = (cA < d1) ? row1[cA] : -1;
    const int s1b = (cB < d1) ? row1[cB] : -1;
    if (s0a >= 0) {
      const uint4 v = h1v[((size_t)s0a << 1) + p];
      upk_add(v.x, A[0], A[1]); upk_add(v.y, A[2], A[3]);
      upk_add(v.z, A[4], A[5]); upk_add(v.w, A[6], A[7]);
    }
    if (s0b >= 0) {
      const uint4 v = h1v[((size_t)s0b << 1) + p];
      upk_add(v.x, A[0], A[1]); upk_add(v.y, A[2], A[3]);
      upk_add(v.z, A[4], A[5]); upk_add(v.w, A[6], A[7]);
    }
    if (s1a >= 0) {
      const uint4 v = h1v[((size_t)s1a << 1) + p];
      upk_add(v.x, B[0], B[1]); upk_add(v.y, B[2], B[3]);
      upk_add(v.z, B[4], B[5]); upk_add(v.w, B[6], B[7]);
    }
    if (s1b >= 0) {
      const uint4 v = h1v[((size_t)s1b << 1) + p];
      upk_add(v.x, B[0], B[1]); upk_add(v.y, B[2], B[3]);
      upk_add(v.z, B[4], B[5]); upk_add(v.w, B[6], B[7]);
    }
  }
  l1_finish(A, i0, d0, lane, p, h1v, b1, W2, h2v);
  if (has1) l1_finish(B, i1, d1, lane, p, h1v, b1, W2, h2v);
}

// ---- layer2 per-node finish: reduce, +self, bias, log_softmax, store -------
__device__ __forceinline__ void l2_finish(float a[8], int i, int d, int lane,
                                          const uint4* __restrict__ h2v,
                                          const float* __restrict__ b2,
                                          float* __restrict__ out) {
#pragma unroll
  for (int m = 1; m <= 32; m <<= 1) {
#pragma unroll
    for (int j = 0; j < 7; ++j) a[j] += __shfl_xor(a[j], m);
  }
  const uint4 v = h2v[i];
  upk_add(v.x, a[0], a[1]);
  upk_add(v.y, a[2], a[3]);
  upk_add(v.z, a[4], a[5]);
  float dummy = 0.f;
  upk_add(v.w, a[6], dummy);
  if (lane == 0) {
    const float sd = rsqrtf((float)(d + 1));
    float vv[7];
#pragma unroll
    for (int j = 0; j < 7; ++j) vv[j] = fmaf(a[j], sd, b2[j]);
    float m = fmaxf(fmaxf(fmaxf(vv[0], vv[1]), fmaxf(vv[2], vv[3])),
                    fmaxf(fmaxf(vv[4], vv[5]), vv[6]));
    float sum = 0.f;
#pragma unroll
    for (int j = 0; j < 7; ++j) sum += expf(vv[j] - m);
    const float l = m + logf(sum);
    float* __restrict__ op = out + (size_t)i * F_OUT;
#pragma unroll
    for (int j = 0; j < 7; ++j) op[j] = vv[j] - l;
  }
}

// ---- layer2 gather: one wave = TWO nodes, indices hoisted ahead of gathers -
__global__ __launch_bounds__(256) void k_agg2n(const int* __restrict__ cnt,
                                               const int* __restrict__ csr,
                                               const uint4* __restrict__ h2v,
                                               const float* __restrict__ b2,
                                               float* __restrict__ out, int N) {
  const int lane = threadIdx.x & 63;
  const int i0 = blockIdx.x * 8 + (threadIdx.x >> 6) * 2;
  if (i0 >= N) return;
  const int i1 = i0 + 1;
  const bool has1 = (i1 < N);

  const int d0 = cnt[i0];
  const int d1 = has1 ? cnt[i1] : 0;
  const int* __restrict__ row0 = csr + ((size_t)i0 << 7);
  const int* __restrict__ row1 = csr + ((size_t)i1 << 7);

  float A[8], B[8];
#pragma unroll
  for (int j = 0; j < 8; ++j) { A[j] = 0.f; B[j] = 0.f; }
  const int dm = max(d0, d1);
  for (int c0 = 0; c0 < dm; c0 += 64) {
    const int c = c0 + lane;
    const int sA = (c < d0) ? row0[c] : -1;
    const int sB = (c < d1) ? row1[c] : -1;
    if (sA >= 0) {
      const uint4 v = h2v[sA];
      upk_add(v.x, A[0], A[1]); upk_add(v.y, A[2], A[3]);
      upk_add(v.z, A[4], A[5]); upk_add(v.w, A[6], A[7]);
    }
    if (sB >= 0) {
      const uint4 v = h2v[sB];
      upk_add(v.x, B[0], B[1]); upk_add(v.y, B[2], B[3]);
      upk_add(v.z, B[4], B[5]); upk_add(v.w, B[6], B[7]);
    }
  }
  l2_finish(A, i0, d0, lane, h2v, b2, out);
  if (has1) l2_finish(B, i1, d1, lane, h2v, b2, out);
}

extern "C" void kernel_launch(void* const* d_in, const int* in_sizes, int n_in,
                              void* d_out, int out_size, void* d_ws,
                              size_t ws_size, hipStream_t stream) {
  const float* x = (const float*)d_in[0];
  const int* ei = (const int*)d_in[1];
  const float* W1 = (const float*)d_in[2];
  const float* b1 = (const float*)d_in[3];
  const float* W2 = (const float*)d_in[4];
  const float* b2 = (const float*)d_in[5];

  const int N = in_sizes[0] / F_IN;
  const int E = in_sizes[1] / 2;
  const int* src = ei;
  const int* dst = ei + E;

  // ws: h1f[16N f32] | h1b[16N bf16] | h2b[8N bf16] | cnt[N] | csr[N*CAP] | W1f
  float* h1f = (float*)d_ws;
  unsigned short* h1b = (unsigned short*)(h1f + (size_t)16 * N);
  unsigned short* h2b = h1b + (size_t)16 * N;
  int* cnt = (int*)(h2b + (size_t)8 * N);
  int* csr = cnt + N;
  uint4* W1f = (uint4*)(csr + (size_t)N * CAP);
  float* out = (float*)d_out;

  const int B = 256;
  const int nzb = (N + B - 1) / B;        // 391
  const int ngb = (N + 63) / 64;          // gemm blocks (64 rows each)

  k_prep<<<nzb + NKT, B, 0, stream>>>(W1, cnt, W1f, N, nzb);
  k_fused<<<NSCAT + ngb, B, 0, stream>>>(x, W1f, src, dst, cnt, csr, h1f, N, E);
  k_scale<<<(2 * N + B - 1) / B, B, 0, stream>>>((const float4*)h1f, cnt,
                                                 (uint4*)h1b, N);
  k_agg1n<<<(N + 7) / 8, B, 0, stream>>>(cnt, csr, (const uint4*)h1b, b1, W2,
                                         (uint4*)h2b, N);
  k_agg2n<<<(N + 7) / 8, B, 0, stream>>>(cnt, csr, (const uint4*)h2b, b2, out,
                                         N);
}